// Round 7
// baseline (139.512 us; speedup 1.0000x reference)
//
#include <hip/hip_runtime.h>
#include <hip/hip_bf16.h>
#include <math.h>

#define BATCH 16
#define SEQ   2048
#define HID   128
#define DIM   64
#define WTP   136   // Wt LDS row pitch (ushorts): 128 + 8 pad -> no b128 conflicts

typedef __attribute__((ext_vector_type(8))) short bf16x8;
typedef __attribute__((ext_vector_type(4))) float f32x4;

// 0.125 (1/sqrt(D)) * log2(e): folded into Wq so MFMA emits log2-domain scores
#define QSCALE 0.18033688011112042f
#define C0_PE  0.07195578314043169f   // ln(10000)/128

static __device__ __forceinline__ ushort f2bf(float f) {
    union { float f; unsigned u; } v; v.f = f;
    unsigned r = v.u + 0x7FFFu + ((v.u >> 16) & 1u);   // RNE
    return (ushort)(r >> 16);
}

static __device__ __forceinline__ float fast_exp2(float x) {
#if __has_builtin(__builtin_amdgcn_exp2f)
    return __builtin_amdgcn_exp2f(x);
#else
    return exp2f(x);
#endif
}

// ---------------------------------------------------------------------------
// QKV + prep fused (MFMA): 256 thr x 512 blocks; block = 64 rows.
// Per-block prep: Wt_lds[outcol][k] = bf16([Wq*QSCALE | Wk]^T), wvf in LDS.
// MFMA with A = Wt tile (m = outcol), B = xp rows (n = row) ->
// lane holds 4 consecutive DIM cols of ONE row -> 8-byte vector stores.
// ---------------------------------------------------------------------------
__global__ __launch_bounds__(256) void k_qkv(
    const float* __restrict__ x, const float* __restrict__ Wq,
    const float* __restrict__ Wk, const float* __restrict__ Wv,
    const float* __restrict__ Wf, ushort* __restrict__ Qb,
    ushort* __restrict__ Kb, float* __restrict__ vf)
{
    __shared__ ushort Wt[128 * WTP];   // ~34 KB
    __shared__ float  wvl[HID];

    const int tid  = threadIdx.x;
    const int wave = tid >> 6;
    const int lane = tid & 63;
    const int quad = lane >> 4;
    const int col  = lane & 15;

    // ---- per-block prep ----
    if (tid < HID) {
        float s = 0.f;
        #pragma unroll 8
        for (int d = 0; d < DIM; ++d) s += Wv[tid * DIM + d] * Wf[d];
        wvl[tid] = s;
    }
    for (int i = tid; i < 128 * 128; i += 256) {
        int k = i >> 7, oc = i & 127;          // read coalesced over oc
        float v = (oc < 64) ? Wq[k * DIM + oc] * QSCALE : Wk[k * DIM + (oc - 64)];
        Wt[oc * WTP + k] = f2bf(v);
    }
    __syncthreads();

    const int rowbase = blockIdx.x * 64 + wave * 16;
    const int grow = rowbase + col;          // this lane's xp row
    const float pos = (float)(grow & (SEQ - 1));

    // ---- build xp fragments (B-side: n = row, k = HID) + vf partial ----
    bf16x8 af[4];
    float vpart = 0.f;
    #pragma unroll
    for (int c = 0; c < 4; ++c) {
        const float* xp = x + (size_t)grow * HID + quad * 8 + c * 32;
        float4 v0 = *(const float4*)(xp);
        float4 v1 = *(const float4*)(xp + 4);
        float t[8] = {v0.x, v0.y, v0.z, v0.w, v1.x, v1.y, v1.z, v1.w};
        #pragma unroll
        for (int jp = 0; jp < 4; ++jp) {
            int h = quad * 8 + c * 32 + jp * 2;      // even
            float ang = pos * __expf(-(float)h * C0_PE);
            t[jp * 2]     += __sinf(ang);
            t[jp * 2 + 1] += __cosf(ang);
        }
        const float* wp = wvl + quad * 8 + c * 32;
        vpart += t[0] * wp[0] + t[1] * wp[1] + t[2] * wp[2] + t[3] * wp[3] +
                 t[4] * wp[4] + t[5] * wp[5] + t[6] * wp[6] + t[7] * wp[7];
        short* ap = (short*)&af[c];
        #pragma unroll
        for (int j = 0; j < 8; ++j) ap[j] = (short)f2bf(t[j]);
    }

    vpart += __shfl_xor(vpart, 16);
    vpart += __shfl_xor(vpart, 32);
    if (quad == 0) vf[grow] = vpart;

    // ---- 8 outcol tiles: 0..3 -> Q (prescaled), 4..7 -> K ----
    #pragma unroll
    for (int t = 0; t < 8; ++t) {
        const ushort* wrow = Wt + (size_t)(t * 16 + col) * WTP + quad * 8;
        f32x4 acc = {0.f, 0.f, 0.f, 0.f};
        #pragma unroll
        for (int c = 0; c < 4; ++c) {
            bf16x8 wfr = *(const bf16x8*)(wrow + c * 32);
            acc = __builtin_amdgcn_mfma_f32_16x16x32_bf16(wfr, af[c], acc, 0, 0, 0);
        }
        // D: row(quad*4+r) = outcol-in-tile, col(lane&15) = xp row
        ushort4 o = {f2bf(acc.x), f2bf(acc.y), f2bf(acc.z), f2bf(acc.w)};
        ushort* dst = (t < 4) ? Qb : Kb;
        *(ushort4*)&dst[(size_t)grow * DIM + (t & 3) * 16 + quad * 4] = o;
    }
}

// ---------------------------------------------------------------------------
// Fused attention (MFMA, transposed orientation): block = (b, 64 k-cols),
// 512 thr = 8 waves.  A = K-frag (m = k), B = Q rows (n = q) ->
// D: row = k, col = q.
// Phase A: l[t][r] reg-accumulate exp2 over q; end-only reduction.
// Phase B: rs (one reg) accumulates exp2*w over all k of this block for
//          q = base+col; per-iter flush = 2 shuffles + 1 atomicAdd.
// ---------------------------------------------------------------------------
__global__ __launch_bounds__(512) void k_attn(
    const ushort* __restrict__ Qb, const ushort* __restrict__ Kb,
    const float* __restrict__ vf, const float* __restrict__ bfp,
    float* __restrict__ outp)
{
    const int b    = blockIdx.y;
    const int k0   = blockIdx.x * 64;
    const int tid  = threadIdx.x;
    const int wave = tid >> 6;
    const int lane = tid & 63;
    const int quad = lane >> 4;
    const int col  = lane & 15;

    __shared__ float sl[8][64];
    __shared__ float wcol[64];

    // resident K fragments (A-side): 4 tiles x 2 chunks
    bf16x8 kf[4][2];
    {
        const ushort* Kbase = Kb + ((size_t)(b * SEQ + k0)) * DIM;
        #pragma unroll
        for (int t = 0; t < 4; ++t)
            #pragma unroll
            for (int c = 0; c < 2; ++c)
                kf[t][c] = *(const bf16x8*)(Kbase + (size_t)(t * 16 + col) * DIM + quad * 8 + c * 32);
    }

    const ushort* Qstart = Qb + ((size_t)(b * SEQ + wave * 256 + col)) * DIM + quad * 8;

    // ---- Phase A: column sums, k in registers ----
    float l[4][4] = {};
    {
        const ushort* Qrow = Qstart;
        for (int qi = 0; qi < 16; ++qi) {
            bf16x8 q0 = *(const bf16x8*)(Qrow);
            bf16x8 q1 = *(const bf16x8*)(Qrow + 32);
            Qrow += 16 * DIM;
            #pragma unroll
            for (int t = 0; t < 4; ++t) {
                f32x4 acc = {0.f, 0.f, 0.f, 0.f};
                acc = __builtin_amdgcn_mfma_f32_16x16x32_bf16(kf[t][0], q0, acc, 0, 0, 0);
                acc = __builtin_amdgcn_mfma_f32_16x16x32_bf16(kf[t][1], q1, acc, 0, 0, 0);
                #pragma unroll
                for (int r = 0; r < 4; ++r)
                    l[t][r] += fast_exp2(acc[r]);
            }
        }
    }
    // end-only reduction over the 16 q-cols
    #pragma unroll
    for (int t = 0; t < 4; ++t)
        #pragma unroll
        for (int r = 0; r < 4; ++r) {
            float v = l[t][r];
            v += __shfl_xor(v, 1); v += __shfl_xor(v, 2);
            v += __shfl_xor(v, 4); v += __shfl_xor(v, 8);
            l[t][r] = v;
        }
    if (col == 0) {
        #pragma unroll
        for (int t = 0; t < 4; ++t)
            #pragma unroll
            for (int r = 0; r < 4; ++r)
                sl[wave][t * 16 + quad * 4 + r] = l[t][r];
    }
    __syncthreads();
    if (tid < 64) {
        float ll = 0.f;
        #pragma unroll
        for (int w = 0; w < 8; ++w) ll += sl[w][tid];
        wcol[tid] = vf[(size_t)b * SEQ + k0 + tid] / ll;
    }
    __syncthreads();

    // ---- Phase B: per-q accumulate over k, in-register ----
    float wreg[4][4];
    #pragma unroll
    for (int t = 0; t < 4; ++t)
        #pragma unroll
        for (int r = 0; r < 4; ++r)
            wreg[t][r] = wcol[t * 16 + quad * 4 + r];

    const float bias = bfp[0] * (1.0f / (SEQ / 64));   // each block adds bf/32
    float* outb = outp + (size_t)b * SEQ;
    {
        const ushort* Qrow = Qstart;
        for (int qi = 0; qi < 16; ++qi) {
            bf16x8 q0 = *(const bf16x8*)(Qrow);
            bf16x8 q1 = *(const bf16x8*)(Qrow + 32);
            Qrow += 16 * DIM;
            float rs = 0.f;
            #pragma unroll
            for (int t = 0; t < 4; ++t) {
                f32x4 acc = {0.f, 0.f, 0.f, 0.f};
                acc = __builtin_amdgcn_mfma_f32_16x16x32_bf16(kf[t][0], q0, acc, 0, 0, 0);
                acc = __builtin_amdgcn_mfma_f32_16x16x32_bf16(kf[t][1], q1, acc, 0, 0, 0);
                #pragma unroll
                for (int r = 0; r < 4; ++r)
                    rs += fast_exp2(acc[r]) * wreg[t][r];
            }
            rs += __shfl_xor(rs, 16);
            rs += __shfl_xor(rs, 32);
            if (quad == 0)
                atomicAdd(&outb[wave * 256 + qi * 16 + col], rs + bias);
        }
    }
}

// ---------------------------------------------------------------------------
extern "C" void kernel_launch(void* const* d_in, const int* in_sizes, int n_in,
                              void* d_out, int out_size, void* d_ws, size_t ws_size,
                              hipStream_t stream) {
    (void)in_sizes; (void)n_in; (void)ws_size;
    const float* x  = (const float*)d_in[0];
    const float* Wq = (const float*)d_in[1];
    const float* Wk = (const float*)d_in[2];
    const float* Wv = (const float*)d_in[3];
    const float* Wf = (const float*)d_in[4];
    const float* bf = (const float*)d_in[5];
    float* outp = (float*)d_out;

    float*  vf = (float*)d_ws;                                   // B*S
    ushort* Qb = (ushort*)(vf + (size_t)BATCH * SEQ);            // B*S*D bf16
    ushort* Kb = Qb + (size_t)BATCH * SEQ * DIM;                 // B*S*D bf16

    hipMemsetAsync(d_out, 0, (size_t)out_size * sizeof(float), stream);
    k_qkv<<<BATCH * SEQ / 64, 256, 0, stream>>>(x, Wq, Wk, Wv, Wf, Qb, Kb, vf);
    k_attn<<<dim3(SEQ / 64, BATCH), 512, 0, stream>>>(Qb, Kb, vf, bf, outp);
}